// Round 8
// baseline (227.517 us; speedup 1.0000x reference)
//
#include <hip/hip_runtime.h>
#include <math.h>
#include <stdint.h>

#define F_INN 128
#define HIDD 64
#define ALPHA 0.2f
#define RPW 13   // rows per wave in k3 (contiguous -> edge streams stay local)

typedef float v4f  __attribute__((ext_vector_type(4)));
typedef float v2f  __attribute__((ext_vector_type(2)));
typedef short s8v  __attribute__((ext_vector_type(8)));

__device__ __forceinline__ float wave_sum(float v) {
    #pragma unroll
    for (int m = 32; m >= 1; m >>= 1) v += __shfl_xor(v, m, 64);
    return v;
}
// fp32 -> bf16 (RNE) and back
__device__ __forceinline__ unsigned short f2bf(float f) {
    unsigned u = __float_as_uint(f);
    return (unsigned short)((u + 0x7FFFu + ((u >> 16) & 1u)) >> 16);
}
__device__ __forceinline__ float bf2f(unsigned short h) {
    return __uint_as_float(((unsigned)h) << 16);
}
// unpack 2 bf16 (packed in a uint) -> v2f
__device__ __forceinline__ v2f unpk(unsigned u) {
    v2f r; r.x = __uint_as_float(u << 16); r.y = __uint_as_float(u & 0xFFFF0000u);
    return r;
}

// K02: block 0 -> w1=W@a1, w2=W@a2; blocks 1..32 -> pack W into MFMA B-frag
// layout (split hi/lo bf16); blocks 33+ -> row_ptr binary search.
__global__ void k02_prep(const float* __restrict__ W, const float* __restrict__ a1,
                         const float* __restrict__ a2, const int* __restrict__ erow,
                         float* __restrict__ w1, float* __restrict__ w2,
                         unsigned short* __restrict__ whF, unsigned short* __restrict__ wlF,
                         int* __restrict__ rptr, int n, int E)
{
    const int tid = threadIdx.x, b = blockIdx.x;
    if (b == 0) {
        if (tid < 128) {
            float s = 0.f;
            for (int h = 0; h < HIDD; ++h) s = fmaf(W[tid * HIDD + h], a1[h], s);
            w1[tid] = s;
        } else {
            const int f = tid - 128;
            float s = 0.f;
            for (int h = 0; h < HIDD; ++h) s = fmaf(W[f * HIDD + h], a2[h], s);
            w2[f] = s;
        }
        return;
    }
    if (b <= 32) {
        const int g = (b - 1) * 256 + tid;
        const int j = g & 7, lane = (g >> 3) & 63, kc = (g >> 9) & 3, nt = (g >> 11) & 3;
        const int k = kc * 32 + (lane >> 4) * 8 + j;
        const int nn = nt * 16 + (lane & 15);
        const float w = W[k * HIDD + nn];
        const unsigned short hi = f2bf(w);
        whF[g] = hi;
        wlF[g] = f2bf(w - bf2f(hi));
        return;
    }
    const int r = (b - 33) * 256 + tid;
    if (r > n) return;
    int lo = 0, hi = E;
    while (lo < hi) {
        int mid = (lo + hi) >> 1;
        if (erow[mid] < r) lo = mid + 1; else hi = mid;
    }
    rptr[r] = lo;
}

// K1: fts16 = bf16(seq @ W) via split-bf16 3-term MFMA (fp32-accurate);
// f1/f2 fused. One wave = 16 nodes; at its ~64 MB memory floor.
__global__ __launch_bounds__(256) void k1_feat(
    const float* __restrict__ seq,
    const unsigned short* __restrict__ whF, const unsigned short* __restrict__ wlF,
    const float* __restrict__ w1, const float* __restrict__ w2,
    const float* __restrict__ b1, const float* __restrict__ b2,
    unsigned short* __restrict__ fts16, float* __restrict__ f1, float* __restrict__ f2,
    int n)
{
    const int lane = threadIdx.x & 63;
    const long wid = blockIdx.x * 4 + (threadIdx.x >> 6);
    const long n0 = wid * 16;
    if (n0 >= n) return;
    const int m = lane & 15, q = lane >> 4, fb = q * 8;
    long nd = n0 + m; if (nd >= n) nd = n - 1;
    const float* srow = seq + nd * F_INN;

    s8v Ah[4], Al[4];
    float p1 = 0.f, p2 = 0.f;
    #pragma unroll
    for (int kc = 0; kc < 4; ++kc) {
        const v4f r0  = *(const v4f*)(srow + kc * 32 + fb);
        const v4f r1  = *(const v4f*)(srow + kc * 32 + fb + 4);
        const v4f u1a = *(const v4f*)(w1 + kc * 32 + fb);
        const v4f u1b = *(const v4f*)(w1 + kc * 32 + fb + 4);
        const v4f u2a = *(const v4f*)(w2 + kc * 32 + fb);
        const v4f u2b = *(const v4f*)(w2 + kc * 32 + fb + 4);
        #pragma unroll
        for (int j = 0; j < 8; ++j) {
            const float x  = (j < 4) ? r0[j] : r1[j - 4];
            const float wa = (j < 4) ? u1a[j] : u1b[j - 4];
            const float wb = (j < 4) ? u2a[j] : u2b[j - 4];
            const unsigned short h = f2bf(x);
            Ah[kc][j] = (short)h;
            Al[kc][j] = (short)f2bf(x - bf2f(h));
            p1 = fmaf(x, wa, p1);
            p2 = fmaf(x, wb, p2);
        }
    }

    v4f acc[4];
    #pragma unroll
    for (int nt = 0; nt < 4; ++nt) acc[nt] = (v4f){0.f, 0.f, 0.f, 0.f};
    #pragma unroll
    for (int nt = 0; nt < 4; ++nt) {
        #pragma unroll
        for (int kc = 0; kc < 4; ++kc) {
            const int fo = ((nt * 4 + kc) * 64 + lane) * 8;
            const s8v Bh = *(const s8v*)(whF + fo);
            const s8v Bl = *(const s8v*)(wlF + fo);
            acc[nt] = __builtin_amdgcn_mfma_f32_16x16x32_bf16(Ah[kc], Bh, acc[nt], 0, 0, 0);
            acc[nt] = __builtin_amdgcn_mfma_f32_16x16x32_bf16(Ah[kc], Bl, acc[nt], 0, 0, 0);
            acc[nt] = __builtin_amdgcn_mfma_f32_16x16x32_bf16(Al[kc], Bh, acc[nt], 0, 0, 0);
        }
    }

    #pragma unroll
    for (int nt = 0; nt < 4; ++nt) {
        #pragma unroll
        for (int reg = 0; reg < 4; ++reg) {
            const long node = n0 + q * 4 + reg;
            if (node < n) fts16[node * HIDD + nt * 16 + m] = f2bf(acc[nt][reg]);
        }
    }
    p1 += __shfl_xor(p1, 16, 64); p1 += __shfl_xor(p1, 32, 64);
    p2 += __shfl_xor(p2, 16, 64); p2 += __shfl_xor(p2, 32, 64);
    if (lane < 16 && n0 + lane < n) {
        f1[n0 + lane] = p1 + b1[0];
        f2[n0 + lane] = p2 + b2[0];
    }
}

// K2b: per-edge logits -> z = exp(lrelu(.)), streamed with full-grid
// parallelism (the serial per-row head removed from K3). 4 edges/thread.
// f1[erow] near-broadcast (sorted), f2[ecol] random 4B in 400 KB (L2-hot).
__global__ __launch_bounds__(256) void k2b_z(
    const int* __restrict__ erow, const int* __restrict__ ecol,
    const float* __restrict__ evals, const float* __restrict__ f1,
    const float* __restrict__ f2, unsigned short* __restrict__ z16, int E)
{
    const int e0 = (blockIdx.x * 256 + threadIdx.x) * 4;
    if (e0 + 3 >= E) {
        for (int e = e0; e < E; ++e) {
            float l = evals[e] * (f1[erow[e]] + f2[ecol[e]]);
            l = (l > 0.f) ? l : ALPHA * l;
            z16[e] = f2bf(__expf(l));
        }
        return;
    }
    const int4 c4 = *(const int4*)(ecol + e0);
    const int4 r4 = *(const int4*)(erow + e0);
    const v4f  v4 = *(const v4f*)(evals + e0);
    float l0 = v4[0] * (f1[r4.x] + f2[c4.x]);
    float l1 = v4[1] * (f1[r4.y] + f2[c4.y]);
    float l2 = v4[2] * (f1[r4.z] + f2[c4.z]);
    float l3 = v4[3] * (f1[r4.w] + f2[c4.w]);
    l0 = (l0 > 0.f) ? l0 : ALPHA * l0;
    l1 = (l1 > 0.f) ? l1 : ALPHA * l1;
    l2 = (l2 > 0.f) ? l2 : ALPHA * l2;
    l3 = (l3 > 0.f) ? l3 : ALPHA * l3;
    ushort4 zz;
    zz.x = f2bf(__expf(l0)); zz.y = f2bf(__expf(l1));
    zz.z = f2bf(__expf(l2)); zz.w = f2bf(__expf(l3));
    *(ushort4*)(z16 + e0) = zz;
}

// Fast-row tail: issue 2G gather loads, prefetch next row's (c,z) chunk in
// their shadow, then consume. One edge per 8 lanes (uint4 = 8 bf16).
template<int G>
__device__ __forceinline__ void row_tail(
    const uint4* __restrict__ fts4, const int2* __restrict__ st,
    int lane, int sub, int hc,
    const int* __restrict__ ecol, const unsigned short* __restrict__ z16,
    int nstart, int nend, bool more, int& cN, float& zN, v2f* acc)
{
    uint4 u[2 * G]; float zj[2 * G];
    #pragma unroll
    for (int p = 0; p < 2 * G; ++p) {
        const int2 cz = st[p * 8 + sub];
        zj[p] = __int_as_float(cz.y);
        u[p]  = fts4[cz.x + hc];
    }
    // prefetch next row chunk 0 under the gather shadow
    int c = 0; float z = 0.f;
    if (more) {
        const int e = nstart + lane;
        if (e < nend) { c = ecol[e]; z = bf2f(z16[e]); }
    }
    cN = c; zN = z;
    #pragma unroll
    for (int p = 0; p < 2 * G; ++p) {
        v2f z2; z2.x = zj[p]; z2.y = zj[p];
        acc[0] = __builtin_elementwise_fma(z2, unpk(u[p].x), acc[0]);
        acc[1] = __builtin_elementwise_fma(z2, unpk(u[p].y), acc[1]);
        acc[2] = __builtin_elementwise_fma(z2, unpk(u[p].z), acc[2]);
        acc[3] = __builtin_elementwise_fma(z2, unpk(u[p].w), acc[3]);
    }
}

// Slow fallback (deg>64 chunks): 16-edge granule.
__device__ __forceinline__ void oct_gather(
    const uint4* __restrict__ fts4, const int2* __restrict__ st,
    int cnt, int sub, int hc, v2f* acc)
{
    const int ngrp = (cnt + 15) >> 4;
    for (int gg = 0; gg < ngrp; ++gg) {
        #pragma unroll
        for (int k = 0; k < 2; ++k) {
            const int2 cz = st[(gg * 2 + k) * 8 + sub];
            const uint4 u = fts4[cz.x + hc];
            const float zjs = __int_as_float(cz.y);
            v2f z2; z2.x = zjs; z2.y = zjs;
            acc[0] = __builtin_elementwise_fma(z2, unpk(u.x), acc[0]);
            acc[1] = __builtin_elementwise_fma(z2, unpk(u.y), acc[1]);
            acc[2] = __builtin_elementwise_fma(z2, unpk(u.z), acc[2]);
            acc[3] = __builtin_elementwise_fma(z2, unpk(u.w), acc[3]);
        }
    }
}

// K3: one wave per row, RPW contiguous rows per wave, software-pipelined:
// row r's gathers fly while row r+1's (c,z) chunk prefetches. Head is just
// two coalesced loads (z precomputed by k2b). LDS-transpose epilogue.
__global__ __launch_bounds__(256) void k3_attn(
    const int* __restrict__ ecol, const unsigned short* __restrict__ z16,
    const int* __restrict__ rptr, const uint4* __restrict__ fts4,
    float* __restrict__ out, int n)
{
    __shared__ int2  stage[4][64];
    __shared__ float red[4][8][64];
    const int lane = threadIdx.x & 63;
    const int wv = threadIdx.x >> 6;
    const long w = blockIdx.x * 4 + wv;
    const int r0 = (int)(w * RPW);
    if (r0 >= n) return;
    const int rend = min(r0 + RPW, n);
    const int sub = lane >> 3, hc = lane & 7;
    int2* st = stage[wv];
    float* rd = &red[wv][0][0];

    // prefetch row r0: meta + first edge chunk
    int start = rptr[r0], end = rptr[r0 + 1];
    int cN = 0; float zN = 0.f;
    {
        const int e = start + lane;
        if (e < end) { cN = ecol[e]; zN = bf2f(z16[e]); }
    }

    for (int r = r0; r < rend; ++r) {
        const int deg = end - start;
        const bool more = (r + 1 < rend);
        const int e2 = more ? rptr[r + 2] : 0;   // end of next row
        st[lane] = make_int2(cN * 8, __float_as_int(zN));
        float s;
        v2f acc[4];
        #pragma unroll
        for (int i = 0; i < 4; ++i) { acc[i].x = 0.f; acc[i].y = 0.f; }

        if (deg <= 64) {
            s = wave_sum(zN);
            const int G = (deg + 15) >> 4;   // 0..4, wave-uniform
            switch (G) {
                case 3:  row_tail<3>(fts4, st, lane, sub, hc, ecol, z16, end, e2, more, cN, zN, acc); break;
                case 4:  row_tail<4>(fts4, st, lane, sub, hc, ecol, z16, end, e2, more, cN, zN, acc); break;
                default: row_tail<2>(fts4, st, lane, sub, hc, ecol, z16, end, e2, more, cN, zN, acc); break;
            }
        } else {
            // rare: multi-chunk row, no pipeline
            float sc = zN;
            oct_gather(fts4, st, 64, sub, hc, acc);
            for (int base = start + 64; base < end; base += 64) {
                const int e = base + lane;
                int c = 0; float z = 0.f;
                if (e < end) { c = ecol[e]; z = bf2f(z16[e]); }
                sc += z;
                st[lane] = make_int2(c * 8, __float_as_int(z));
                oct_gather(fts4, st, min(64, end - base), sub, hc, acc);
            }
            s = wave_sum(sc);
            cN = 0; zN = 0.f;
            if (more) {
                const int e = end + lane;
                if (e < e2) { cN = ecol[e]; zN = bf2f(z16[e]); }
            }
        }

        // epilogue: LDS transpose, 8-way sum, ELU, coalesced 256B store
        *(v4f*)(rd + sub * 64 + hc * 8)     = (v4f){acc[0].x, acc[0].y, acc[1].x, acc[1].y};
        *(v4f*)(rd + sub * 64 + hc * 8 + 4) = (v4f){acc[2].x, acc[2].y, acc[3].x, acc[3].y};
        const float inv = (deg > 0) ? __builtin_amdgcn_rcpf(s) : 0.f;
        float t = 0.f;
        #pragma unroll
        for (int i = 0; i < 8; ++i) t += rd[i * 64 + lane];
        float v = t * inv;
        v = (v > 0.f) ? v : (__expf(v) - 1.f);
        out[(size_t)r * HIDD + lane] = v;

        start = end; end = e2;   // advance meta
    }
}

extern "C" void kernel_launch(void* const* d_in, const int* in_sizes, int n_in,
                              void* d_out, int out_size, void* d_ws, size_t ws_size,
                              hipStream_t stream)
{
    const float* seq   = (const float*)d_in[0];
    const int*   erow  = (const int*)  d_in[1];
    const int*   ecol  = (const int*)  d_in[2];
    const float* evals = (const float*)d_in[3];
    const float* W     = (const float*)d_in[4];
    const float* a1    = (const float*)d_in[5];
    const float* b1    = (const float*)d_in[6];
    const float* a2    = (const float*)d_in[7];
    const float* b2    = (const float*)d_in[8];
    // d_in[9] = bias_zero (zeros) — additive no-op, skipped.

    const int N = in_sizes[0] / F_INN;
    const int E = in_sizes[1];

    // workspace: fts16 | z16 | f1 | f2 | rptr | w1 | w2 | whF | wlF (~21 MB)
    char* p = (char*)d_ws;
    unsigned short* fts16 = (unsigned short*)p; p += (size_t)N * HIDD * 2;
    unsigned short* z16   = (unsigned short*)p; p += (size_t)E * 2;
    float* f1 = (float*)p; p += (size_t)N * 4;
    float* f2 = (float*)p; p += (size_t)N * 4;
    int* rptr = (int*)p;   p += (size_t)(N + 1) * 4;
    p = (char*)(((uintptr_t)p + 15) & ~(uintptr_t)15);
    float* w1 = (float*)p; p += 128 * 4;
    float* w2 = (float*)p; p += 128 * 4;
    unsigned short* whF = (unsigned short*)p; p += 8192 * 2;
    unsigned short* wlF = (unsigned short*)p;

    float* out = (float*)d_out;

    const int rblocks = (N + 1 + 255) / 256;
    k02_prep<<<33 + rblocks, 256, 0, stream>>>(W, a1, a2, erow, w1, w2,
                                               whF, wlF, rptr, N, E);

    const int waves1  = (N + 15) / 16;
    const int blocks1 = (waves1 + 3) / 4;
    k1_feat<<<blocks1, 256, 0, stream>>>(seq, whF, wlF, w1, w2, b1, b2,
                                         fts16, f1, f2, N);

    const int eblocks = (E + 1023) / 1024;
    k2b_z<<<eblocks, 256, 0, stream>>>(erow, ecol, evals, f1, f2, z16, E);

    const int waves3  = (N + RPW - 1) / RPW;
    const int blocks3 = (waves3 + 3) / 4;
    k3_attn<<<blocks3, 256, 0, stream>>>(ecol, z16, rptr,
                                         (const uint4*)fts16, out, N);
}